// Round 4
// baseline (625.248 us; speedup 1.0000x reference)
//
#include <hip/hip_runtime.h>
#include <hip/hip_bf16.h>

// 3-layer GCN: h = A_norm * (x @ W) + b per layer, relu between.
// GEMMs on MFMA via split-bf16 (x = hi+lo, A@B ~= AhBh+AhBl+AlBh, fp32 accum).
// Aggregation via fixed-slot CSR. Degrees ~ Poisson(16); SLOTS=48 overflow
// prob ~1e-10/node, agg guards with min(cnt,48).
// 128-wide messages bf16 (halves gather traffic); agg128 packs 2 nodes per wave
// (half-wave x ushort4 = 512B per gather instruction).
//
// R1: GEMMs latency-bound -> 64-row tiles + reg-staged pipeline (590 -> 555us).
// R2: nt-loads on fill: FAILED. 8x redundant scan was structural.
// R3: two-phase bucket CSR build: NEUTRAL (556us). Fill off the top-5.
// R4: GEMMs still #1 (77us, MfmaUtil 9.5%, 4.8M LDS conflicts, floor ~20us).
//     For a 128-col GEMM with L2-resident weights the LDS round-trip is pure
//     overhead: load MFMA fragments DIRECTLY global->reg (A: 2x float4/lane,
//     split in-register; B: short8v from pre-split Wth/Wtl). Zero LDS, zero
//     barriers, zero bank conflicts; compiler free to pipeline loads across
//     the fully-unrolled K-loop. Bitwise-identical numerics.

#define WAVE 64
#define SLOTS 48

#define BKT_NR 8
#define BKT_CAP 208000      // per-bucket cap: E/8=200k expected, +8k ~ 19 sigma
#define BKT_BLK_E 2048      // edges per block in bucket pass
#define FILL2_NCHB 196      // chunks per range in fill pass (8*196 blocks)

typedef short short8v __attribute__((ext_vector_type(8)));
typedef float f32x4 __attribute__((ext_vector_type(4)));

__device__ inline void split_bf16(float v, ushort& hi, ushort& lo) {
    __hip_bfloat16 h = __float2bfloat16(v);
    float hf = __bfloat162float(h);
    __hip_bfloat16 l = __float2bfloat16(v - hf);
    hi = *reinterpret_cast<ushort*>(&h);
    lo = *reinterpret_cast<ushort*>(&l);
}

__device__ inline float bf2f(ushort u) {
    unsigned int t = ((unsigned int)u) << 16;
    return __uint_as_float(t);
}

__device__ inline ushort f2bf(float v) {
    __hip_bfloat16 h = __float2bfloat16(v);
    return *reinterpret_cast<ushort*>(&h);
}

// split two float4 (8 consecutive fp32) into hi/lo bf16 fragment vectors
__device__ inline void split8(const float4& x, const float4& y, short8v& h, short8v& l) {
    ushort hh, ll;
    split_bf16(x.x, hh, ll); h[0] = (short)hh; l[0] = (short)ll;
    split_bf16(x.y, hh, ll); h[1] = (short)hh; l[1] = (short)ll;
    split_bf16(x.z, hh, ll); h[2] = (short)hh; l[2] = (short)ll;
    split_bf16(x.w, hh, ll); h[3] = (short)hh; l[3] = (short)ll;
    split_bf16(y.x, hh, ll); h[4] = (short)hh; l[4] = (short)ll;
    split_bf16(y.y, hh, ll); h[5] = (short)hh; l[5] = (short)ll;
    split_bf16(y.z, hh, ll); h[6] = (short)hh; l[6] = (short)ll;
    split_bf16(y.w, hh, ll); h[7] = (short)hh; l[7] = (short)ll;
}

// ---------------- Phase A: bucket edges by dst range ----------------

__global__ __launch_bounds__(256) void k_bucket(const int* __restrict__ src,
                                                const int* __restrict__ dst,
                                                int* __restrict__ bcnt,
                                                long long* __restrict__ buckets,
                                                int E, int N) {
    __shared__ int lcnt[BKT_NR];
    __shared__ int lbase[BKT_NR];
    const int tid = threadIdx.x;
    const int lo = blockIdx.x * BKT_BLK_E;
    const int hi = min(lo + BKT_BLK_E, E);
    if (tid < BKT_NR) lcnt[tid] = 0;
    __syncthreads();

    int r[8], rank[8], sv[8], dv[8];
#pragma unroll
    for (int u = 0; u < 8; ++u) {
        int e = lo + tid + u * 256;
        if (e < hi) {
            int d = __builtin_nontemporal_load(&dst[e]);
            int s = __builtin_nontemporal_load(&src[e]);
            int rr = (int)(((long long)d * BKT_NR) / N);
            r[u] = rr;
            sv[u] = s;
            dv[u] = d;
            rank[u] = atomicAdd(&lcnt[rr], 1);
        } else {
            r[u] = -1;
        }
    }
    __syncthreads();
    if (tid < BKT_NR) lbase[tid] = atomicAdd(&bcnt[tid], lcnt[tid]);
    __syncthreads();
#pragma unroll
    for (int u = 0; u < 8; ++u) {
        if (r[u] >= 0) {
            int pos = lbase[r[u]] + rank[u];
            if (pos < BKT_CAP) {
                long long v = ((long long)dv[u] << 32) | (unsigned int)sv[u];
                __builtin_nontemporal_store(v, &buckets[(size_t)r[u] * BKT_CAP + pos]);
            }
        }
    }
}

// ---------------- Phase B: per-range fill (XCD-affine) ----------------

__global__ __launch_bounds__(256) void k_fill_bucket(const long long* __restrict__ buckets,
                                                     const int* __restrict__ bcnt,
                                                     int* __restrict__ cnt,
                                                     int* __restrict__ slots) {
    int b = blockIdx.x;
    int r = b & (BKT_NR - 1);
    int cb = b >> 3;
    int nb = bcnt[r];
    if (nb > BKT_CAP) nb = BKT_CAP;
    const long long* bk = buckets + (size_t)r * BKT_CAP;
    for (int i = cb * 256 + threadIdx.x; i < nb; i += FILL2_NCHB * 256) {
        long long v = __builtin_nontemporal_load(&bk[i]);
        int s = (int)v;
        int d = (int)(v >> 32);
        int p = atomicAdd(&cnt[d], 1);
        if (p < SLOTS) slots[(size_t)d * SLOTS + p] = s;
    }
}

__global__ void k_dinv(const int* __restrict__ cnt, float* __restrict__ dinv, int N) {
    int i = blockIdx.x * blockDim.x + threadIdx.x;
    if (i < N) dinv[i] = rsqrtf((float)cnt[i] + 1.0f);
}

// ---------------- W pre-split: W[K][M] fp32 -> Wt_hi/lo[Mpad][K] bf16 (transposed) ----------------

__global__ void k_wsplit(const float* __restrict__ W, ushort* __restrict__ Wth,
                         ushort* __restrict__ Wtl, int K, int M, int Mpad) {
    int idx = blockIdx.x * 256 + threadIdx.x;
    if (idx >= K * Mpad) return;
    int k = idx / Mpad, m = idx % Mpad;
    float v = (m < M) ? W[(size_t)k * M + m] : 0.f;
    ushort h, l;
    split_bf16(v, h, l);
    Wth[(size_t)m * K + k] = h;
    Wtl[(size_t)m * K + k] = l;
}

// ---------------- MFMA GEMM, 128 cols, 64-row tile, direct global->reg ----------------
// 4 waves: wave&1 -> row half (32 rows), wave>>1 -> col half (64). acc[2][4].
// No LDS, no barriers: fragments loaded straight from global (A via float4
// pairs + in-reg split; B via short8v from L2-resident pre-split weights).

template <int K, bool BF16OUT>
__global__ __launch_bounds__(256) void gemm_mfma128(const float* __restrict__ A,
                                                    const ushort* __restrict__ Wth,
                                                    const ushort* __restrict__ Wtl,
                                                    const float* __restrict__ rowscale,
                                                    void* __restrict__ outv, int N) {
    const int tid = threadIdx.x;
    const int lane = tid & 63, wave = tid >> 6;
    const int wr = (wave & 1) * 32, wc = (wave >> 1) * 64;
    const int r0 = blockIdx.x * 64;
    const int tr = lane & 15, quad = lane >> 4;

    int row0 = r0 + wr + tr;       if (row0 > N - 1) row0 = N - 1;
    int row1 = r0 + wr + 16 + tr;  if (row1 > N - 1) row1 = N - 1;
    const float* Ap0 = A + (size_t)row0 * K + quad * 8;
    const float* Ap1 = A + (size_t)row1 * K + quad * 8;
    const ushort* Bhp = Wth + (size_t)(wc + tr) * K + quad * 8;
    const ushort* Blp = Wtl + (size_t)(wc + tr) * K + quad * 8;

    f32x4 acc[2][4];
#pragma unroll
    for (int i = 0; i < 2; ++i)
#pragma unroll
        for (int j = 0; j < 4; ++j) acc[i][j] = (f32x4)(0.f);

#pragma unroll
    for (int kc = 0; kc < K; kc += 32) {
        float4 a00 = *reinterpret_cast<const float4*>(Ap0 + kc);
        float4 a01 = *reinterpret_cast<const float4*>(Ap0 + kc + 4);
        float4 a10 = *reinterpret_cast<const float4*>(Ap1 + kc);
        float4 a11 = *reinterpret_cast<const float4*>(Ap1 + kc + 4);
        short8v bh[4], bl[4];
#pragma unroll
        for (int j = 0; j < 4; ++j) {
            bh[j] = *reinterpret_cast<const short8v*>(Bhp + (size_t)j * 16 * K + kc);
            bl[j] = *reinterpret_cast<const short8v*>(Blp + (size_t)j * 16 * K + kc);
        }
        short8v ah[2], al[2];
        split8(a00, a01, ah[0], al[0]);
        split8(a10, a11, ah[1], al[1]);
#pragma unroll
        for (int i = 0; i < 2; ++i)
#pragma unroll
            for (int j = 0; j < 4; ++j) {
                acc[i][j] = __builtin_amdgcn_mfma_f32_16x16x32_bf16(ah[i], bh[j], acc[i][j], 0, 0, 0);
                acc[i][j] = __builtin_amdgcn_mfma_f32_16x16x32_bf16(ah[i], bl[j], acc[i][j], 0, 0, 0);
                acc[i][j] = __builtin_amdgcn_mfma_f32_16x16x32_bf16(al[i], bh[j], acc[i][j], 0, 0, 0);
            }
    }

#pragma unroll
    for (int i = 0; i < 2; ++i) {
        int rbase = r0 + wr + i * 16 + quad * 4;
        float rs[4];
#pragma unroll
        for (int reg = 0; reg < 4; ++reg) {
            int r = rbase + reg;
            rs[reg] = (r < N) ? rowscale[r] : 0.f;
        }
#pragma unroll
        for (int j = 0; j < 4; ++j) {
            int c = wc + j * 16 + tr;
#pragma unroll
            for (int reg = 0; reg < 4; ++reg) {
                int r = rbase + reg;
                if (r < N) {
                    float v = acc[i][j][reg] * rs[reg];
                    if (BF16OUT)
                        ((ushort*)outv)[(size_t)r * 128 + c] = f2bf(v);
                    else
                        ((float*)outv)[(size_t)r * 128 + c] = v;
                }
            }
        }
    }
}

// ---------------- MFMA GEMM, 40 cols (padded to 48), K=128, direct global->reg ----------------
// 4 waves x 16 rows each, 48 cols (j=0..2). acc[3]. No LDS, no barriers.

__global__ __launch_bounds__(256) void gemm_mfma40(const float* __restrict__ A,
                                                   const ushort* __restrict__ Wth,
                                                   const ushort* __restrict__ Wtl,
                                                   const float* __restrict__ rowscale,
                                                   float* __restrict__ out, int N) {
    constexpr int K = 128, M = 40;
    const int tid = threadIdx.x;
    const int lane = tid & 63, wave = tid >> 6;
    const int wr = wave * 16;
    const int r0 = blockIdx.x * 64;
    const int tr = lane & 15, quad = lane >> 4;

    int row0 = r0 + wr + tr;  if (row0 > N - 1) row0 = N - 1;
    const float* Ap0 = A + (size_t)row0 * K + quad * 8;
    const ushort* Bhp = Wth + (size_t)tr * K + quad * 8;
    const ushort* Blp = Wtl + (size_t)tr * K + quad * 8;

    f32x4 acc[3];
#pragma unroll
    for (int j = 0; j < 3; ++j) acc[j] = (f32x4)(0.f);

#pragma unroll
    for (int kc = 0; kc < K; kc += 32) {
        float4 a0 = *reinterpret_cast<const float4*>(Ap0 + kc);
        float4 a1 = *reinterpret_cast<const float4*>(Ap0 + kc + 4);
        short8v bh[3], bl[3];
#pragma unroll
        for (int j = 0; j < 3; ++j) {
            bh[j] = *reinterpret_cast<const short8v*>(Bhp + (size_t)j * 16 * K + kc);
            bl[j] = *reinterpret_cast<const short8v*>(Blp + (size_t)j * 16 * K + kc);
        }
        short8v ah, al;
        split8(a0, a1, ah, al);
#pragma unroll
        for (int j = 0; j < 3; ++j) {
            acc[j] = __builtin_amdgcn_mfma_f32_16x16x32_bf16(ah, bh[j], acc[j], 0, 0, 0);
            acc[j] = __builtin_amdgcn_mfma_f32_16x16x32_bf16(ah, bl[j], acc[j], 0, 0, 0);
            acc[j] = __builtin_amdgcn_mfma_f32_16x16x32_bf16(al, bh[j], acc[j], 0, 0, 0);
        }
    }

    {
        int rbase = r0 + wr + quad * 4;
        float rs[4];
#pragma unroll
        for (int reg = 0; reg < 4; ++reg) {
            int r = rbase + reg;
            rs[reg] = (r < N) ? rowscale[r] : 0.f;
        }
#pragma unroll
        for (int j = 0; j < 3; ++j) {
            int c = j * 16 + tr;
#pragma unroll
            for (int reg = 0; reg < 4; ++reg) {
                int r = rbase + reg;
                if (r < N && c < M) out[(size_t)r * M + c] = acc[j][reg] * rs[reg];
            }
        }
    }
}

// ---------------- aggregation, 128-wide bf16: 2 nodes per wave ----------------

template <bool RELU>
__global__ __launch_bounds__(256) void agg128_bf2(const ushort* __restrict__ S,
                                                  const int* __restrict__ slots,
                                                  const int* __restrict__ cnt,
                                                  const float* __restrict__ dinv,
                                                  const float* __restrict__ bias,
                                                  float* __restrict__ out, int N) {
    int w = (blockIdx.x * blockDim.x + threadIdx.x) >> 6;
    int lane = threadIdx.x & 63;
    int npair = (N + 1) >> 1;
    if (w >= npair) return;
    int half = lane >> 5, sub = lane & 31;
    int node = 2 * w + half;
    bool valid = node < N;
    int snode = valid ? node : 0;
    const ushort4* S4 = (const ushort4*)S;  // row = 32 x ushort4
    const int* row = slots + (size_t)snode * SLOTS;
    int c = valid ? cnt[snode] : 0;
    if (c > SLOTS) c = SLOTS;
    int cmax = max(c, __shfl(c, lane ^ 32));

    ushort4 sv = S4[(size_t)snode * 32 + sub];  // self loop
    float a0 = bf2f(sv.x), a1 = bf2f(sv.y), a2 = bf2f(sv.z), a3 = bf2f(sv.w);

    int e = 0;
    for (; e + 8 <= cmax; e += 8) {
        int s[8];
#pragma unroll
        for (int u = 0; u < 8; ++u) s[u] = (e + u < c) ? row[e + u] : snode;
        ushort4 v[8];
#pragma unroll
        for (int u = 0; u < 8; ++u) v[u] = S4[(size_t)s[u] * 32 + sub];
#pragma unroll
        for (int u = 0; u < 8; ++u) {
            float m = (e + u < c) ? 1.f : 0.f;
            a0 += m * bf2f(v[u].x);
            a1 += m * bf2f(v[u].y);
            a2 += m * bf2f(v[u].z);
            a3 += m * bf2f(v[u].w);
        }
    }
    for (; e < cmax; ++e) {
        int s = (e < c) ? row[e] : snode;
        ushort4 v = S4[(size_t)s * 32 + sub];
        float m = (e < c) ? 1.f : 0.f;
        a0 += m * bf2f(v.x);
        a1 += m * bf2f(v.y);
        a2 += m * bf2f(v.z);
        a3 += m * bf2f(v.w);
    }

    if (valid) {
        float di = dinv[node];
        float4 bv = ((const float4*)bias)[sub];
        float o0 = a0 * di + bv.x;
        float o1 = a1 * di + bv.y;
        float o2 = a2 * di + bv.z;
        float o3 = a3 * di + bv.w;
        if (RELU) {
            o0 = fmaxf(o0, 0.f);
            o1 = fmaxf(o1, 0.f);
            o2 = fmaxf(o2, 0.f);
            o3 = fmaxf(o3, 0.f);
        }
        ((float4*)out)[(size_t)node * 32 + sub] = make_float4(o0, o1, o2, o3);
    }
}

// fp32 messages, M=40 (final layer), wave per node
__global__ __launch_bounds__(256) void agg40(const float* __restrict__ S,
                                             const int* __restrict__ slots,
                                             const int* __restrict__ cnt,
                                             const float* __restrict__ dinv,
                                             const float* __restrict__ bias,
                                             float* __restrict__ out, int N) {
    int wid = (blockIdx.x * blockDim.x + threadIdx.x) >> 6;
    int lane = threadIdx.x & 63;
    if (wid >= N || lane >= 40) return;
    const int* row = slots + (size_t)wid * SLOTS;
    int c = cnt[wid];
    if (c > SLOTS) c = SLOTS;
    float acc = S[(size_t)wid * 40 + lane];
    int e = 0;
    for (; e + 8 <= c; e += 8) {
        int s[8];
#pragma unroll
        for (int u = 0; u < 8; ++u) s[u] = row[e + u];
        float v[8];
#pragma unroll
        for (int u = 0; u < 8; ++u) v[u] = S[(size_t)s[u] * 40 + lane];
#pragma unroll
        for (int u = 0; u < 8; ++u) acc += v[u];
    }
    for (; e < c; ++e) acc += S[(size_t)row[e] * 40 + lane];
    out[(size_t)wid * 40 + lane] = acc * dinv[wid] + bias[lane];
}

// ---------------- launch ----------------

extern "C" void kernel_launch(void* const* d_in, const int* in_sizes, int n_in,
                              void* d_out, int out_size, void* d_ws, size_t ws_size,
                              hipStream_t stream) {
    const float* x  = (const float*)d_in[0];
    const int*   ei = (const int*)d_in[1];
    const float* W1 = (const float*)d_in[2];
    const float* b1 = (const float*)d_in[3];
    const float* W2 = (const float*)d_in[4];
    const float* b2 = (const float*)d_in[5];
    const float* W3 = (const float*)d_in[6];
    const float* b3 = (const float*)d_in[7];
    float* out = (float*)d_out;

    const int IN_DIM = 256, HID = 128;
    const int N = in_sizes[0] / IN_DIM;
    const int E = in_sizes[1] / 2;
    const int* srcE = ei;
    const int* dstE = ei + E;

    char* ws = (char*)d_ws;
    size_t off = 0;
    auto alloc = [&](size_t bytes) -> void* {
        off = (off + 255) & ~(size_t)255;
        void* p = ws + off;
        off += bytes;
        return p;
    };
    int*    cnt   = (int*)alloc((size_t)N * 4);
    int*    bcnt  = (int*)alloc((size_t)BKT_NR * 4);
    float*  dinv  = (float*)alloc((size_t)N * 4);
    int*    slots = (int*)alloc((size_t)N * SLOTS * 4);     // 19.2 MB
    long long* buckets = (long long*)alloc((size_t)BKT_NR * BKT_CAP * 8);  // 13.3 MB
    ushort* bufS  = (ushort*)alloc((size_t)N * HID * 4);    // bf16 msgs (128) or fp32 msgs (40)
    float*  bufH  = (float*)alloc((size_t)N * HID * 4);     // fp32 h
    ushort* W1th  = (ushort*)alloc((size_t)128 * 256 * 2);
    ushort* W1tl  = (ushort*)alloc((size_t)128 * 256 * 2);
    ushort* W2th  = (ushort*)alloc((size_t)128 * 128 * 2);
    ushort* W2tl  = (ushort*)alloc((size_t)128 * 128 * 2);
    ushort* W3th  = (ushort*)alloc((size_t)48 * 128 * 2);
    ushort* W3tl  = (ushort*)alloc((size_t)48 * 128 * 2);

    const int NB = (N + 255) / 256;
    const int AGGB = (N * WAVE + 255) / 256;
    const int AGG2B = (((N + 1) / 2) * WAVE + 255) / 256;
    const int GB64 = (N + 63) / 64;
    const int BKTB = (E + BKT_BLK_E - 1) / BKT_BLK_E;

    // W pre-split (tiny)
    k_wsplit<<<(256 * 128 + 255) / 256, 256, 0, stream>>>(W1, W1th, W1tl, 256, 128, 128);
    k_wsplit<<<(128 * 128 + 255) / 256, 256, 0, stream>>>(W2, W2th, W2tl, 128, 128, 128);
    k_wsplit<<<(128 * 48 + 255) / 256, 256, 0, stream>>>(W3, W3th, W3tl, 128, 40, 48);

    // two-phase CSR build + dinv
    hipMemsetAsync(cnt, 0, (size_t)N * 4, stream);
    hipMemsetAsync(bcnt, 0, (size_t)BKT_NR * 4, stream);
    k_bucket<<<BKTB, 256, 0, stream>>>(srcE, dstE, bcnt, buckets, E, N);
    k_fill_bucket<<<BKT_NR * FILL2_NCHB, 256, 0, stream>>>(buckets, bcnt, cnt, slots);
    k_dinv<<<NB, 256, 0, stream>>>(cnt, dinv, N);

    // Layer 1: 256 -> 128, relu (bf16 messages)
    gemm_mfma128<256, true><<<GB64, 256, 0, stream>>>(x, W1th, W1tl, dinv, bufS, N);
    agg128_bf2<true><<<AGG2B, 256, 0, stream>>>(bufS, slots, cnt, dinv, b1, bufH, N);
    // Layer 2: 128 -> 128, relu (bf16 messages)
    gemm_mfma128<128, true><<<GB64, 256, 0, stream>>>(bufH, W2th, W2tl, dinv, bufS, N);
    agg128_bf2<true><<<AGG2B, 256, 0, stream>>>(bufS, slots, cnt, dinv, b2, bufH, N);
    // Layer 3: 128 -> 40, no relu (fp32 messages)
    gemm_mfma40<<<GB64, 256, 0, stream>>>(bufH, W3th, W3tl, dinv, (float*)bufS, N);
    agg40<<<AGGB, 256, 0, stream>>>((float*)bufS, slots, cnt, dinv, b3, out, N);
}

// Round 5
// 561.108 us; speedup vs baseline: 1.1143x; 1.1143x over previous
//
#include <hip/hip_runtime.h>
#include <hip/hip_bf16.h>

// 3-layer GCN: h = A_norm * (x @ W) + b per layer, relu between.
// GEMMs on MFMA via split-bf16 (x = hi+lo, A@B ~= AhBh+AhBl+AlBh, fp32 accum).
// Aggregation via fixed-slot CSR. Degrees ~ Poisson(16); SLOTS=48 overflow
// prob ~1e-10/node, agg guards with min(cnt,48).
//
// R1: GEMMs latency-bound -> 64-row tiles + reg-staged pipeline (590 -> 555us).
// R2: nt-loads on fill: FAILED. 8x redundant scan was structural.
// R3: two-phase bucket CSR build: NEUTRAL (556us best). Fill off the top-5.
// R4: all-direct-from-global GEMM: FAILED (77 -> 116us). MFMA operands off L2
//     latency with 68 VGPRs = per-fragment stalls. Lesson: B must be in LDS.
// R5: hybrid. B in LDS staged per BK=64 chunk (subtile-40 layout, barriers
//     16 -> 7 for K=256); A-fragments direct global->reg (streaming operand,
//     coalesced). Layers 2-3 consume PRE-SPLIT hi/lo bf16 A planes emitted by
//     agg128's epilogue (same split values -> bitwise-identical numerics);
//     layer 1 splits fp32 x in-register. Zero split VALU in layers 2-3.

#define WAVE 64
#define SLOTS 48

#define BKT_NR 8
#define BKT_CAP 208000      // per-bucket cap: E/8=200k expected, +8k ~ 19 sigma
#define BKT_BLK_E 2048      // edges per block in bucket pass
#define FILL2_NCHB 196      // chunks per range in fill pass (8*196 blocks)

typedef short short8v __attribute__((ext_vector_type(8)));
typedef float f32x4 __attribute__((ext_vector_type(4)));

__device__ inline void split_bf16(float v, ushort& hi, ushort& lo) {
    __hip_bfloat16 h = __float2bfloat16(v);
    float hf = __bfloat162float(h);
    __hip_bfloat16 l = __float2bfloat16(v - hf);
    hi = *reinterpret_cast<ushort*>(&h);
    lo = *reinterpret_cast<ushort*>(&l);
}

__device__ inline float bf2f(ushort u) {
    unsigned int t = ((unsigned int)u) << 16;
    return __uint_as_float(t);
}

__device__ inline ushort f2bf(float v) {
    __hip_bfloat16 h = __float2bfloat16(v);
    return *reinterpret_cast<ushort*>(&h);
}

// split two float4 (8 consecutive fp32) into hi/lo bf16 fragment vectors
__device__ inline void split8(const float4& x, const float4& y, short8v& h, short8v& l) {
    ushort hh, ll;
    split_bf16(x.x, hh, ll); h[0] = (short)hh; l[0] = (short)ll;
    split_bf16(x.y, hh, ll); h[1] = (short)hh; l[1] = (short)ll;
    split_bf16(x.z, hh, ll); h[2] = (short)hh; l[2] = (short)ll;
    split_bf16(x.w, hh, ll); h[3] = (short)hh; l[3] = (short)ll;
    split_bf16(y.x, hh, ll); h[4] = (short)hh; l[4] = (short)ll;
    split_bf16(y.y, hh, ll); h[5] = (short)hh; l[5] = (short)ll;
    split_bf16(y.z, hh, ll); h[6] = (short)hh; l[6] = (short)ll;
    split_bf16(y.w, hh, ll); h[7] = (short)hh; l[7] = (short)ll;
}

// ---------------- Phase A: bucket edges by dst range ----------------

__global__ __launch_bounds__(256) void k_bucket(const int* __restrict__ src,
                                                const int* __restrict__ dst,
                                                int* __restrict__ bcnt,
                                                long long* __restrict__ buckets,
                                                int E, int N) {
    __shared__ int lcnt[BKT_NR];
    __shared__ int lbase[BKT_NR];
    const int tid = threadIdx.x;
    const int lo = blockIdx.x * BKT_BLK_E;
    const int hi = min(lo + BKT_BLK_E, E);
    if (tid < BKT_NR) lcnt[tid] = 0;
    __syncthreads();

    int r[8], rank[8], sv[8], dv[8];
#pragma unroll
    for (int u = 0; u < 8; ++u) {
        int e = lo + tid + u * 256;
        if (e < hi) {
            int d = __builtin_nontemporal_load(&dst[e]);
            int s = __builtin_nontemporal_load(&src[e]);
            int rr = (int)(((long long)d * BKT_NR) / N);
            r[u] = rr;
            sv[u] = s;
            dv[u] = d;
            rank[u] = atomicAdd(&lcnt[rr], 1);
        } else {
            r[u] = -1;
        }
    }
    __syncthreads();
    if (tid < BKT_NR) lbase[tid] = atomicAdd(&bcnt[tid], lcnt[tid]);
    __syncthreads();
#pragma unroll
    for (int u = 0; u < 8; ++u) {
        if (r[u] >= 0) {
            int pos = lbase[r[u]] + rank[u];
            if (pos < BKT_CAP) {
                long long v = ((long long)dv[u] << 32) | (unsigned int)sv[u];
                __builtin_nontemporal_store(v, &buckets[(size_t)r[u] * BKT_CAP + pos]);
            }
        }
    }
}

// ---------------- Phase B: per-range fill (XCD-affine) ----------------

__global__ __launch_bounds__(256) void k_fill_bucket(const long long* __restrict__ buckets,
                                                     const int* __restrict__ bcnt,
                                                     int* __restrict__ cnt,
                                                     int* __restrict__ slots) {
    int b = blockIdx.x;
    int r = b & (BKT_NR - 1);
    int cb = b >> 3;
    int nb = bcnt[r];
    if (nb > BKT_CAP) nb = BKT_CAP;
    const long long* bk = buckets + (size_t)r * BKT_CAP;
    for (int i = cb * 256 + threadIdx.x; i < nb; i += FILL2_NCHB * 256) {
        long long v = __builtin_nontemporal_load(&bk[i]);
        int s = (int)v;
        int d = (int)(v >> 32);
        int p = atomicAdd(&cnt[d], 1);
        if (p < SLOTS) slots[(size_t)d * SLOTS + p] = s;
    }
}

__global__ void k_dinv(const int* __restrict__ cnt, float* __restrict__ dinv, int N) {
    int i = blockIdx.x * blockDim.x + threadIdx.x;
    if (i < N) dinv[i] = rsqrtf((float)cnt[i] + 1.0f);
}

// ---------------- W pre-split: W[K][M] fp32 -> Wt_hi/lo[Mpad][K] bf16 (transposed) ----------------

__global__ void k_wsplit(const float* __restrict__ W, ushort* __restrict__ Wth,
                         ushort* __restrict__ Wtl, int K, int M, int Mpad) {
    int idx = blockIdx.x * 256 + threadIdx.x;
    if (idx >= K * Mpad) return;
    int k = idx / Mpad, m = idx % Mpad;
    float v = (m < M) ? W[(size_t)k * M + m] : 0.f;
    ushort h, l;
    split_bf16(v, h, l);
    Wth[(size_t)m * K + k] = h;
    Wtl[(size_t)m * K + k] = l;
}

// ---------------- MFMA GEMM, 128 cols, 64-row tile ----------------
// 4 waves: wave&1 -> row half (32 rows), wave>>1 -> col half (64). acc[2][4].
// B staged to LDS in BK=64 chunks ([ks][col][LD40] subtile layout, same
// fragment semantics as R3). A fragments direct global->reg: PRESPLIT reads
// hi/lo bf16 planes; else fp32 + in-register split8. 7 barriers total (K=256).

template <int K, bool PRESPLIT>
__global__ __launch_bounds__(256) void gemm_mfma128(const void* __restrict__ Av,
                                                    const ushort* __restrict__ Alg,
                                                    const ushort* __restrict__ Wth,
                                                    const ushort* __restrict__ Wtl,
                                                    const float* __restrict__ rowscale,
                                                    ushort* __restrict__ outv, int N) {
    constexpr int LD = 40;
    __shared__ ushort Bh[2 * 128 * LD], Bl[2 * 128 * LD];  // [ks][col][LD]

    const int tid = threadIdx.x;
    const int lane = tid & 63, wave = tid >> 6;
    const int wr = (wave & 1) * 32, wc = (wave >> 1) * 64;
    const int r0 = blockIdx.x * 64;
    const int tr = lane & 15, quad = lane >> 4;

    int row0 = r0 + wr + tr;       if (row0 > N - 1) row0 = N - 1;
    int row1 = r0 + wr + 16 + tr;  if (row1 > N - 1) row1 = N - 1;

    const float* Af0 = nullptr;
    const float* Af1 = nullptr;
    const ushort* Ah0 = nullptr;
    const ushort* Ah1 = nullptr;
    const ushort* Al0 = nullptr;
    const ushort* Al1 = nullptr;
    if constexpr (PRESPLIT) {
        const ushort* Ahg = (const ushort*)Av;
        Ah0 = Ahg + (size_t)row0 * K + quad * 8;
        Ah1 = Ahg + (size_t)row1 * K + quad * 8;
        Al0 = Alg + (size_t)row0 * K + quad * 8;
        Al1 = Alg + (size_t)row1 * K + quad * 8;
    } else {
        const float* Af = (const float*)Av;
        Af0 = Af + (size_t)row0 * K + quad * 8;
        Af1 = Af + (size_t)row1 * K + quad * 8;
    }

    // B staging: thread -> (col = tid>>1, ks = tid&1); 64B per plane per stage
    const int scol = tid >> 1, sks = tid & 1;
    const ushort* WhS = Wth + (size_t)scol * K + sks * 32;
    const ushort* WlS = Wtl + (size_t)scol * K + sks * 32;
    ushort* BhD = &Bh[(sks * 128 + scol) * LD];
    ushort* BlD = &Bl[(sks * 128 + scol) * LD];

    f32x4 acc[2][4];
#pragma unroll
    for (int i = 0; i < 2; ++i)
#pragma unroll
        for (int j = 0; j < 4; ++j) acc[i][j] = (f32x4)(0.f);

    for (int kc0 = 0; kc0 < K; kc0 += 64) {
        if (kc0 > 0) __syncthreads();  // previous chunk's reads done before overwrite
#pragma unroll
        for (int p = 0; p < 4; ++p) {
            *reinterpret_cast<uint4*>(BhD + p * 8) =
                *reinterpret_cast<const uint4*>(WhS + kc0 + p * 8);
            *reinterpret_cast<uint4*>(BlD + p * 8) =
                *reinterpret_cast<const uint4*>(WlS + kc0 + p * 8);
        }
        __syncthreads();

        // hoist both substeps' A fragment loads
        short8v ahA[2], alA[2], ahB[2], alB[2];
        if constexpr (PRESPLIT) {
            ahA[0] = *reinterpret_cast<const short8v*>(Ah0 + kc0);
            ahA[1] = *reinterpret_cast<const short8v*>(Ah1 + kc0);
            alA[0] = *reinterpret_cast<const short8v*>(Al0 + kc0);
            alA[1] = *reinterpret_cast<const short8v*>(Al1 + kc0);
            ahB[0] = *reinterpret_cast<const short8v*>(Ah0 + kc0 + 32);
            ahB[1] = *reinterpret_cast<const short8v*>(Ah1 + kc0 + 32);
            alB[0] = *reinterpret_cast<const short8v*>(Al0 + kc0 + 32);
            alB[1] = *reinterpret_cast<const short8v*>(Al1 + kc0 + 32);
        } else {
            float4 a00 = *reinterpret_cast<const float4*>(Af0 + kc0);
            float4 a01 = *reinterpret_cast<const float4*>(Af0 + kc0 + 4);
            float4 a10 = *reinterpret_cast<const float4*>(Af1 + kc0);
            float4 a11 = *reinterpret_cast<const float4*>(Af1 + kc0 + 4);
            float4 b00 = *reinterpret_cast<const float4*>(Af0 + kc0 + 32);
            float4 b01 = *reinterpret_cast<const float4*>(Af0 + kc0 + 36);
            float4 b10 = *reinterpret_cast<const float4*>(Af1 + kc0 + 32);
            float4 b11 = *reinterpret_cast<const float4*>(Af1 + kc0 + 36);
            split8(a00, a01, ahA[0], alA[0]);
            split8(a10, a11, ahA[1], alA[1]);
            split8(b00, b01, ahB[0], alB[0]);
            split8(b10, b11, ahB[1], alB[1]);
        }

#pragma unroll
        for (int ks = 0; ks < 2; ++ks) {
            const short8v* ah = (ks == 0) ? ahA : ahB;
            const short8v* al = (ks == 0) ? alA : alB;
            short8v bh[4], bl[4];
#pragma unroll
            for (int j = 0; j < 4; ++j) {
                int col = wc + j * 16 + tr;
                bh[j] = *reinterpret_cast<const short8v*>(&Bh[(ks * 128 + col) * LD + quad * 8]);
                bl[j] = *reinterpret_cast<const short8v*>(&Bl[(ks * 128 + col) * LD + quad * 8]);
            }
#pragma unroll
            for (int i = 0; i < 2; ++i)
#pragma unroll
                for (int j = 0; j < 4; ++j) {
                    acc[i][j] = __builtin_amdgcn_mfma_f32_16x16x32_bf16(ah[i], bh[j], acc[i][j], 0, 0, 0);
                    acc[i][j] = __builtin_amdgcn_mfma_f32_16x16x32_bf16(ah[i], bl[j], acc[i][j], 0, 0, 0);
                    acc[i][j] = __builtin_amdgcn_mfma_f32_16x16x32_bf16(al[i], bh[j], acc[i][j], 0, 0, 0);
                }
        }
    }

#pragma unroll
    for (int i = 0; i < 2; ++i) {
        int rbase = r0 + wr + i * 16 + quad * 4;
        float rs[4];
#pragma unroll
        for (int reg = 0; reg < 4; ++reg) {
            int r = rbase + reg;
            rs[reg] = (r < N) ? rowscale[r] : 0.f;
        }
#pragma unroll
        for (int j = 0; j < 4; ++j) {
            int c = wc + j * 16 + tr;
#pragma unroll
            for (int reg = 0; reg < 4; ++reg) {
                int r = rbase + reg;
                if (r < N) outv[(size_t)r * 128 + c] = f2bf(acc[i][j][reg] * rs[reg]);
            }
        }
    }
}

// ---------------- MFMA GEMM, 40 cols (padded to 48), K=128, presplit A ----------------
// 4 waves x 16 rows. B staged per BK=64 chunk ([ks][col48][LD40], 15KB LDS).

__global__ __launch_bounds__(256) void gemm_mfma40(const ushort* __restrict__ Ahg,
                                                   const ushort* __restrict__ Alg,
                                                   const ushort* __restrict__ Wth,
                                                   const ushort* __restrict__ Wtl,
                                                   const float* __restrict__ rowscale,
                                                   float* __restrict__ out, int N) {
    constexpr int K = 128, LD = 40, M = 40;
    __shared__ ushort Bh[2 * 48 * LD], Bl[2 * 48 * LD];

    const int tid = threadIdx.x;
    const int lane = tid & 63, wave = tid >> 6;
    const int wr = wave * 16;
    const int r0 = blockIdx.x * 64;
    const int tr = lane & 15, quad = lane >> 4;

    int row0 = r0 + wr + tr;  if (row0 > N - 1) row0 = N - 1;
    const ushort* Ah0 = Ahg + (size_t)row0 * K + quad * 8;
    const ushort* Al0 = Alg + (size_t)row0 * K + quad * 8;

    const int scol = tid >> 1, sks = tid & 1;  // active for tid < 96
    const bool sact = tid < 96;

    f32x4 acc[3];
#pragma unroll
    for (int j = 0; j < 3; ++j) acc[j] = (f32x4)(0.f);

    for (int kc0 = 0; kc0 < K; kc0 += 64) {
        if (kc0 > 0) __syncthreads();
        if (sact) {
            const ushort* WhS = Wth + (size_t)scol * K + sks * 32 + kc0;
            const ushort* WlS = Wtl + (size_t)scol * K + sks * 32 + kc0;
            ushort* BhD = &Bh[(sks * 48 + scol) * LD];
            ushort* BlD = &Bl[(sks * 48 + scol) * LD];
#pragma unroll
            for (int p = 0; p < 4; ++p) {
                *reinterpret_cast<uint4*>(BhD + p * 8) =
                    *reinterpret_cast<const uint4*>(WhS + p * 8);
                *reinterpret_cast<uint4*>(BlD + p * 8) =
                    *reinterpret_cast<const uint4*>(WlS + p * 8);
            }
        }
        __syncthreads();

        short8v ahA = *reinterpret_cast<const short8v*>(Ah0 + kc0);
        short8v alA = *reinterpret_cast<const short8v*>(Al0 + kc0);
        short8v ahB = *reinterpret_cast<const short8v*>(Ah0 + kc0 + 32);
        short8v alB = *reinterpret_cast<const short8v*>(Al0 + kc0 + 32);

#pragma unroll
        for (int ks = 0; ks < 2; ++ks) {
            short8v ah = (ks == 0) ? ahA : ahB;
            short8v al = (ks == 0) ? alA : alB;
            short8v bh[3], bl[3];
#pragma unroll
            for (int j = 0; j < 3; ++j) {
                int col = j * 16 + tr;
                bh[j] = *reinterpret_cast<const short8v*>(&Bh[(ks * 48 + col) * LD + quad * 8]);
                bl[j] = *reinterpret_cast<const short8v*>(&Bl[(ks * 48 + col) * LD + quad * 8]);
            }
#pragma unroll
            for (int j = 0; j < 3; ++j) {
                acc[j] = __builtin_amdgcn_mfma_f32_16x16x32_bf16(ah, bh[j], acc[j], 0, 0, 0);
                acc[j] = __builtin_amdgcn_mfma_f32_16x16x32_bf16(ah, bl[j], acc[j], 0, 0, 0);
                acc[j] = __builtin_amdgcn_mfma_f32_16x16x32_bf16(al, bh[j], acc[j], 0, 0, 0);
            }
        }
    }

    {
        int rbase = r0 + wr + quad * 4;
        float rs[4];
#pragma unroll
        for (int reg = 0; reg < 4; ++reg) {
            int r = rbase + reg;
            rs[reg] = (r < N) ? rowscale[r] : 0.f;
        }
#pragma unroll
        for (int j = 0; j < 3; ++j) {
            int c = j * 16 + tr;
#pragma unroll
            for (int reg = 0; reg < 4; ++reg) {
                int r = rbase + reg;
                if (r < N && c < M) out[(size_t)r * M + c] = acc[j][reg] * rs[reg];
            }
        }
    }
}

// ---------------- aggregation, 128-wide bf16: 2 nodes per wave ----------------
// Epilogue emits PRE-SPLIT hi/lo bf16 planes (exactly split_bf16 of the fp32
// result) for the next layer's GEMM.

template <bool RELU>
__global__ __launch_bounds__(256) void agg128_bf2(const ushort* __restrict__ S,
                                                  const int* __restrict__ slots,
                                                  const int* __restrict__ cnt,
                                                  const float* __restrict__ dinv,
                                                  const float* __restrict__ bias,
                                                  ushort* __restrict__ outh,
                                                  ushort* __restrict__ outl, int N) {
    int w = (blockIdx.x * blockDim.x + threadIdx.x) >> 6;
    int lane = threadIdx.x & 63;
    int npair = (N + 1) >> 1;
    if (w >= npair) return;
    int half = lane >> 5, sub = lane & 31;
    int node = 2 * w + half;
    bool valid = node < N;
    int snode = valid ? node : 0;
    const ushort4* S4 = (const ushort4*)S;  // row = 32 x ushort4
    const int* row = slots + (size_t)snode * SLOTS;
    int c = valid ? cnt[snode] : 0;
    if (c > SLOTS) c = SLOTS;
    int cmax = max(c, __shfl(c, lane ^ 32));

    ushort4 sv = S4[(size_t)snode * 32 + sub];  // self loop
    float a0 = bf2f(sv.x), a1 = bf2f(sv.y), a2 = bf2f(sv.z), a3 = bf2f(sv.w);

    int e = 0;
    for (; e + 8 <= cmax; e += 8) {
        int s[8];
#pragma unroll
        for (int u = 0; u < 8; ++u) s[u] = (e + u < c) ? row[e + u] : snode;
        ushort4 v[8];
#pragma unroll
        for (int u = 0; u < 8; ++u) v[u] = S4[(size_t)s[u] * 32 + sub];
#pragma unroll
        for (int u = 0; u < 8; ++u) {
            float m = (e + u < c) ? 1.f : 0.f;
            a0 += m * bf2f(v[u].x);
            a1 += m * bf2f(v[u].y);
            a2 += m * bf2f(v[u].z);
            a3 += m * bf2f(v[u].w);
        }
    }
    for (; e < cmax; ++e) {
        int s = (e < c) ? row[e] : snode;
        ushort4 v = S4[(size_t)s * 32 + sub];
        float m = (e < c) ? 1.f : 0.f;
        a0 += m * bf2f(v.x);
        a1 += m * bf2f(v.y);
        a2 += m * bf2f(v.z);
        a3 += m * bf2f(v.w);
    }

    if (valid) {
        float di = dinv[node];
        float4 bv = ((const float4*)bias)[sub];
        float o0 = a0 * di + bv.x;
        float o1 = a1 * di + bv.y;
        float o2 = a2 * di + bv.z;
        float o3 = a3 * di + bv.w;
        if (RELU) {
            o0 = fmaxf(o0, 0.f);
            o1 = fmaxf(o1, 0.f);
            o2 = fmaxf(o2, 0.f);
            o3 = fmaxf(o3, 0.f);
        }
        ushort4 hv, lv;
        split_bf16(o0, hv.x, lv.x);
        split_bf16(o1, hv.y, lv.y);
        split_bf16(o2, hv.z, lv.z);
        split_bf16(o3, hv.w, lv.w);
        ((ushort4*)outh)[(size_t)node * 32 + sub] = hv;
        ((ushort4*)outl)[(size_t)node * 32 + sub] = lv;
    }
}

// fp32 messages, M=40 (final layer), wave per node
__global__ __launch_bounds__(256) void agg40(const float* __restrict__ S,
                                             const int* __restrict__ slots,
                                             const int* __restrict__ cnt,
                                             const float* __restrict__ dinv,
                                             const float* __restrict__ bias,
                                             float* __restrict__ out, int N) {
    int wid = (blockIdx.x * blockDim.x + threadIdx.x) >> 6;
    int lane = threadIdx.x & 63;
    if (wid >= N || lane >= 40) return;
    const int* row = slots + (size_t)wid * SLOTS;
    int c = cnt[wid];
    if (c > SLOTS) c = SLOTS;
    float acc = S[(size_t)wid * 40 + lane];
    int e = 0;
    for (; e + 8 <= c; e += 8) {
        int s[8];
#pragma unroll
        for (int u = 0; u < 8; ++u) s[u] = row[e + u];
        float v[8];
#pragma unroll
        for (int u = 0; u < 8; ++u) v[u] = S[(size_t)s[u] * 40 + lane];
#pragma unroll
        for (int u = 0; u < 8; ++u) acc += v[u];
    }
    for (; e < c; ++e) acc += S[(size_t)row[e] * 40 + lane];
    out[(size_t)wid * 40 + lane] = acc * dinv[wid] + bias[lane];
}

// ---------------- launch ----------------

extern "C" void kernel_launch(void* const* d_in, const int* in_sizes, int n_in,
                              void* d_out, int out_size, void* d_ws, size_t ws_size,
                              hipStream_t stream) {
    const float* x  = (const float*)d_in[0];
    const int*   ei = (const int*)d_in[1];
    const float* W1 = (const float*)d_in[2];
    const float* b1 = (const float*)d_in[3];
    const float* W2 = (const float*)d_in[4];
    const float* b2 = (const float*)d_in[5];
    const float* W3 = (const float*)d_in[6];
    const float* b3 = (const float*)d_in[7];
    float* out = (float*)d_out;

    const int IN_DIM = 256, HID = 128;
    const int N = in_sizes[0] / IN_DIM;
    const int E = in_sizes[1] / 2;
    const int* srcE = ei;
    const int* dstE = ei + E;

    char* ws = (char*)d_ws;
    size_t off = 0;
    auto alloc = [&](size_t bytes) -> void* {
        off = (off + 255) & ~(size_t)255;
        void* p = ws + off;
        off += bytes;
        return p;
    };
    int*    cnt   = (int*)alloc((size_t)N * 4);
    int*    bcnt  = (int*)alloc((size_t)BKT_NR * 4);
    float*  dinv  = (float*)alloc((size_t)N * 4);
    int*    slots = (int*)alloc((size_t)N * SLOTS * 4);     // 19.2 MB
    long long* buckets = (long long*)alloc((size_t)BKT_NR * BKT_CAP * 8);  // 13.3 MB
    ushort* bufS  = (ushort*)alloc((size_t)N * HID * 4);    // bf16 msgs (128) or fp32 msgs (40)
    ushort* Hh    = (ushort*)alloc((size_t)N * HID * 2);    // presplit hidden, hi plane
    ushort* Hl    = (ushort*)alloc((size_t)N * HID * 2);    // presplit hidden, lo plane
    ushort* W1th  = (ushort*)alloc((size_t)128 * 256 * 2);
    ushort* W1tl  = (ushort*)alloc((size_t)128 * 256 * 2);
    ushort* W2th  = (ushort*)alloc((size_t)128 * 128 * 2);
    ushort* W2tl  = (ushort*)alloc((size_t)128 * 128 * 2);
    ushort* W3th  = (ushort*)alloc((size_t)48 * 128 * 2);
    ushort* W3tl  = (ushort*)alloc((size_t)48 * 128 * 2);

    const int NB = (N + 255) / 256;
    const int AGGB = (N * WAVE + 255) / 256;
    const int AGG2B = (((N + 1) / 2) * WAVE + 255) / 256;
    const int GB64 = (N + 63) / 64;
    const int BKTB = (E + BKT_BLK_E - 1) / BKT_BLK_E;

    // W pre-split (tiny)
    k_wsplit<<<(256 * 128 + 255) / 256, 256, 0, stream>>>(W1, W1th, W1tl, 256, 128, 128);
    k_wsplit<<<(128 * 128 + 255) / 256, 256, 0, stream>>>(W2, W2th, W2tl, 128, 128, 128);
    k_wsplit<<<(128 * 48 + 255) / 256, 256, 0, stream>>>(W3, W3th, W3tl, 128, 40, 48);

    // two-phase CSR build + dinv
    hipMemsetAsync(cnt, 0, (size_t)N * 4, stream);
    hipMemsetAsync(bcnt, 0, (size_t)BKT_NR * 4, stream);
    k_bucket<<<BKTB, 256, 0, stream>>>(srcE, dstE, bcnt, buckets, E, N);
    k_fill_bucket<<<BKT_NR * FILL2_NCHB, 256, 0, stream>>>(buckets, bcnt, cnt, slots);
    k_dinv<<<NB, 256, 0, stream>>>(cnt, dinv, N);

    // Layer 1: 256 -> 128, relu (bf16 messages); A = fp32 x, split in-register
    gemm_mfma128<256, false><<<GB64, 256, 0, stream>>>(x, nullptr, W1th, W1tl, dinv, bufS, N);
    agg128_bf2<true><<<AGG2B, 256, 0, stream>>>(bufS, slots, cnt, dinv, b1, Hh, Hl, N);
    // Layer 2: 128 -> 128, relu; A = presplit hidden
    gemm_mfma128<128, true><<<GB64, 256, 0, stream>>>(Hh, Hl, W2th, W2tl, dinv, bufS, N);
    agg128_bf2<true><<<AGG2B, 256, 0, stream>>>(bufS, slots, cnt, dinv, b2, Hh, Hl, N);
    // Layer 3: 128 -> 40, no relu (fp32 messages); A = presplit hidden
    gemm_mfma40<<<GB64, 256, 0, stream>>>(Hh, Hl, W3th, W3tl, dinv, (float*)bufS, N);
    agg40<<<AGGB, 256, 0, stream>>>((float*)bufS, slots, cnt, dinv, b3, out, N);
}